// Round 7
// baseline (521.406 us; speedup 1.0000x reference)
//
#include <hip/hip_runtime.h>
#include <math.h>

#define BB      2
#define LSEQ    2048
#define DMODEL  1024
#define DINNER  2048
#define DSTATE  16
#define DTRANK  64
#define NPROJ   96                 // DTRANK + 2*DSTATE
#define MROWS   (BB * LSEQ)        // 4096
#define NCHUNK  64
#define CLEN    32                 // LSEQ / NCHUNK
#define XKS     16                 // x_proj split-K factor

typedef unsigned short u16;
typedef short bf16x8 __attribute__((ext_vector_type(8)));
typedef float f32x4  __attribute__((ext_vector_type(4)));

// ---------------------------------------------------------------------------
// fp32 -> (hi, lo) bf16 split: v ~= hi + lo, hi = truncate, lo = RNE(residual)
// ---------------------------------------------------------------------------
struct HL { unsigned int hx, hy, lx, ly; };

__device__ __forceinline__ HL cvt4(float4 v) {
  unsigned int tx = __float_as_uint(v.x) & 0xFFFF0000u;
  unsigned int ty = __float_as_uint(v.y) & 0xFFFF0000u;
  unsigned int tz = __float_as_uint(v.z) & 0xFFFF0000u;
  unsigned int tw = __float_as_uint(v.w) & 0xFFFF0000u;
  HL r;
  r.hx = (tx >> 16) | ty;
  r.hy = (tz >> 16) | tw;
  float lx = v.x - __uint_as_float(tx);
  float ly = v.y - __uint_as_float(ty);
  float lz = v.z - __uint_as_float(tz);
  float lw = v.w - __uint_as_float(tw);
  unsigned int a = __float_as_uint(lx); a += 0x7FFFu + ((a >> 16) & 1u);
  unsigned int b = __float_as_uint(ly); b += 0x7FFFu + ((b >> 16) & 1u);
  unsigned int c = __float_as_uint(lz); c += 0x7FFFu + ((c >> 16) & 1u);
  unsigned int d = __float_as_uint(lw); d += 0x7FFFu + ((d >> 16) & 1u);
  r.lx = (a >> 16) | (b & 0xFFFF0000u);
  r.ly = (c >> 16) | (d & 0xFFFF0000u);
  return r;
}

// prep: fp32 array -> hi/lo bf16 planes
__global__ __launch_bounds__(256)
void cvt_hl(const float4* __restrict__ src, uint2* __restrict__ dh,
            uint2* __restrict__ dl, int n4) {
  int i = blockIdx.x * 256 + threadIdx.x;
  if (i < n4) {
    HL r = cvt4(src[i]);
    dh[i] = make_uint2(r.hx, r.hy);
    dl[i] = make_uint2(r.lx, r.ly);
  }
}

// ---------------------------------------------------------------------------
// global_load_lds width-16 wrapper (LDS dest: wave-uniform base + lane*16)
// ---------------------------------------------------------------------------
__device__ __forceinline__ void gll16(const void* g, void* l) {
  __builtin_amdgcn_global_load_lds(
      (const __attribute__((address_space(1))) void*)g,
      (__attribute__((address_space(3))) void*)l, 16, 0, 0);
}

// ---------------------------------------------------------------------------
// Split-bf16 MFMA GEMM from pre-built h/l planes (bf16 [M][K] / [N][K]):
// C = Ah*Bh + Ah*Bl + Al*Bh  (~fp32).  128x128 tile, BK=32, 4 waves (2x2),
// 4x4 16x16x32 frags/wave.  Staging via global_load_lds (no VGPR roundtrip),
// linear LDS dest + source-permuted XOR swizzle (slot ^= (row>>1)&3) matched
// on the ds_read side -> 2-way bank aliasing (free).  Per-XCD 2D supertile
// remap for L2.  Dual output: col<Nout -> C0 else C1 (row stride Nout).
// grid = (M/128)*(N/128) % 8 == 0.
// ---------------------------------------------------------------------------
__global__ __launch_bounds__(256, 3)
void gemm_hl(const u16* __restrict__ Ahp, const u16* __restrict__ Alp,
             const u16* __restrict__ Bhp, const u16* __restrict__ Blp,
             float* __restrict__ C0, float* __restrict__ C1,
             int M, int N, int K, int Nout, int XC_C) {
  __shared__ __align__(16) u16 L[4][128 * 32];   // Ah, Al, Bh, Bl : 32 KB

  const int tid = threadIdx.x;
  const int nbx = N >> 7, nby = M >> 7;
  // per-XCD supertile: chunks arranged (8/XC_C) x XC_C; row-major inside
  const int xcd = blockIdx.x & 7;
  const int pos = blockIdx.x >> 3;
  const int cr = xcd / XC_C, cc = xcd - cr * XC_C;
  const int GCc = nbx / XC_C;
  const int GR  = (nby * XC_C) >> 3;
  const int by = cr * GR + pos / GCc;
  const int bx = cc * GCc + pos % GCc;
  const int row0 = by << 7, col0 = bx << 7;

  const int lane = tid & 63, w = tid >> 6;
  const int wr = w >> 1, wc = w & 1;
  const int fr = lane & 15, g = lane >> 4;
  const int lrow = lane >> 2, lslot = lane & 3;

  f32x4 acc[4][4] = {};

  for (int k0 = 0; k0 < K; k0 += 32) {
#pragma unroll
    for (int s = 0; s < 2; ++s) {
      const int r = w * 32 + s * 16 + lrow;          // tile row this lane fills
      const int csrc = (lslot ^ ((r >> 1) & 3)) << 3; // inverse-swizzled source
      const size_t gA = (size_t)(row0 + r) * K + k0 + csrc;
      const size_t gB = (size_t)(col0 + r) * K + k0 + csrc;
      const int lb = w * 1024 + s * 512;             // wave-uniform LDS base
      gll16(Ahp + gA, &L[0][lb]);
      gll16(Alp + gA, &L[1][lb]);
      gll16(Bhp + gB, &L[2][lb]);
      gll16(Blp + gB, &L[3][lb]);
    }
    __syncthreads();

    bf16x8 bh[4], bl[4];
#pragma unroll
    for (int j = 0; j < 4; ++j) {
      const int rb = wc * 64 + j * 16 + fr;
      const int o = rb * 32 + ((g ^ ((rb >> 1) & 3)) << 3);
      bh[j] = *(const bf16x8*)&L[2][o];
      bl[j] = *(const bf16x8*)&L[3][o];
    }
#pragma unroll
    for (int i = 0; i < 4; ++i) {
      const int ra = wr * 64 + i * 16 + fr;
      const int o = ra * 32 + ((g ^ ((ra >> 1) & 3)) << 3);
      bf16x8 ah = *(const bf16x8*)&L[0][o];
      bf16x8 al = *(const bf16x8*)&L[1][o];
#pragma unroll
      for (int j = 0; j < 4; ++j) {
        acc[i][j] = __builtin_amdgcn_mfma_f32_16x16x32_bf16(al, bh[j], acc[i][j], 0, 0, 0);
        acc[i][j] = __builtin_amdgcn_mfma_f32_16x16x32_bf16(ah, bl[j], acc[i][j], 0, 0, 0);
        acc[i][j] = __builtin_amdgcn_mfma_f32_16x16x32_bf16(ah, bh[j], acc[i][j], 0, 0, 0);
      }
    }
    __syncthreads();
  }

  // C/D layout (m89-verified): col = lane&15, row = (lane>>4)*4 + reg
  float* Cd;
  int cc0;
  if (C1 != nullptr && col0 >= Nout) { Cd = C1; cc0 = col0 - Nout; }
  else                               { Cd = C0; cc0 = col0; }
#pragma unroll
  for (int i = 0; i < 4; ++i) {
    const int rbase = row0 + wr * 64 + i * 16 + (lane >> 4) * 4;
#pragma unroll
    for (int j = 0; j < 4; ++j) {
      const int cfull = cc0 + wc * 64 + j * 16 + fr;
#pragma unroll
      for (int r = 0; r < 4; ++r)
        Cd[(size_t)(rbase + r) * Nout + cfull] = acc[i][j][r];
    }
  }
}

// ---------------------------------------------------------------------------
// fp32 GEMM (dt_proj only): C = softplus(A@B^T + bias[col]); reg prefetch.
// ---------------------------------------------------------------------------
template <int ACT>
__global__ __launch_bounds__(256)
void gemm_tn(const float* __restrict__ A, const float* __restrict__ B,
             float* __restrict__ C, const float* __restrict__ bias,
             int M, int N, int K, int lda) {
  __shared__ float As[8][128];
  __shared__ float Bs[8][128];
  const int tid  = threadIdx.x;
  const int row0 = blockIdx.y * 128;
  const int col0 = blockIdx.x * 128;
  const int tx = tid & 15, ty = tid >> 4;
  const int lr = tid >> 1;
  const int lk = (tid & 1) * 4;

  float acc[8][8];
#pragma unroll
  for (int i = 0; i < 8; ++i)
#pragma unroll
    for (int j = 0; j < 8; ++j) acc[i][j] = 0.f;

  const float* Aptr = A + (size_t)(row0 + lr) * lda + lk;
  const int bcol = col0 + lr;
  const float* Bptr = (bcol < N) ? (B + (size_t)bcol * K + lk) : nullptr;

  float4 av = *(const float4*)(Aptr);
  float4 bv = Bptr ? *(const float4*)(Bptr) : make_float4(0.f, 0.f, 0.f, 0.f);

  for (int k0 = 0; k0 < K; k0 += 8) {
    As[lk + 0][lr] = av.x; As[lk + 1][lr] = av.y;
    As[lk + 2][lr] = av.z; As[lk + 3][lr] = av.w;
    Bs[lk + 0][lr] = bv.x; Bs[lk + 1][lr] = bv.y;
    Bs[lk + 2][lr] = bv.z; Bs[lk + 3][lr] = bv.w;
    if (k0 + 8 < K) {
      av = *(const float4*)(Aptr + k0 + 8);
      if (Bptr) bv = *(const float4*)(Bptr + k0 + 8);
    }
    __syncthreads();
#pragma unroll
    for (int k = 0; k < 8; ++k) {
      float a[8], b[8];
      *(float4*)&a[0] = *(const float4*)&As[k][ty * 4];
      *(float4*)&a[4] = *(const float4*)&As[k][64 + ty * 4];
      *(float4*)&b[0] = *(const float4*)&Bs[k][tx * 4];
      *(float4*)&b[4] = *(const float4*)&Bs[k][64 + tx * 4];
#pragma unroll
      for (int i = 0; i < 8; ++i)
#pragma unroll
        for (int j = 0; j < 8; ++j)
          acc[i][j] = fmaf(a[i], b[j], acc[i][j]);
    }
    __syncthreads();
  }

#pragma unroll
  for (int ih = 0; ih < 2; ++ih) {
#pragma unroll
    for (int i2 = 0; i2 < 4; ++i2) {
      int r = row0 + ih * 64 + ty * 4 + i2;
      if (r >= M) continue;
#pragma unroll
      for (int jh = 0; jh < 2; ++jh) {
        int c = col0 + jh * 64 + tx * 4;
        float vv[4];
#pragma unroll
        for (int j = 0; j < 4; ++j) {
          float v = acc[ih * 4 + i2][jh * 4 + j];
          if (ACT == 1) {
            v += bias[c + j];
            v = (v > 20.f) ? v : log1pf(expf(v));   // softplus
          }
          vv[j] = v;
        }
        if (c + 3 < N) {
          *(float4*)(C + (size_t)r * N + c) = make_float4(vv[0], vv[1], vv[2], vv[3]);
        } else {
          for (int j = 0; j < 4; ++j)
            if (c + j < N) C[(size_t)r * N + c + j] = vv[j];
        }
      }
    }
  }
}

// ---------------------------------------------------------------------------
// x_proj split-K, atomic-free: Pq[q][4096][96] = A[:, q-slice] @ W[:, q-slice]^T
// ---------------------------------------------------------------------------
__global__ __launch_bounds__(256)
void xproj_splitk(const float* __restrict__ A, const float* __restrict__ W,
                  float* __restrict__ Pq) {
  __shared__ float As[8][128];
  __shared__ float Ws[8][96];
  const int tid  = threadIdx.x;
  const int row0 = blockIdx.x * 128;
  const int k0b  = blockIdx.y * (DINNER / XKS);
  const int tx = tid & 15, ty = tid >> 4;
  const int lr = tid >> 1, lk = (tid & 1) * 4;

  float acc[8][6];
#pragma unroll
  for (int i = 0; i < 8; ++i)
#pragma unroll
    for (int j = 0; j < 6; ++j) acc[i][j] = 0.f;

  const float* Ap = A + (size_t)(row0 + lr) * DINNER + lk;
  const float* Wp = (tid < 192) ? (W + (size_t)(tid >> 1) * DINNER + (tid & 1) * 4)
                                : nullptr;
  float4 av = *(const float4*)(Ap + k0b);
  float4 wv = Wp ? *(const float4*)(Wp + k0b) : make_float4(0.f, 0.f, 0.f, 0.f);

  for (int k0 = k0b; k0 < k0b + DINNER / XKS; k0 += 8) {
    As[lk + 0][lr] = av.x; As[lk + 1][lr] = av.y;
    As[lk + 2][lr] = av.z; As[lk + 3][lr] = av.w;
    if (Wp) {
      int j = tid >> 1, kk = (tid & 1) * 4;
      Ws[kk + 0][j] = wv.x; Ws[kk + 1][j] = wv.y;
      Ws[kk + 2][j] = wv.z; Ws[kk + 3][j] = wv.w;
    }
    if (k0 + 8 < k0b + DINNER / XKS) {
      av = *(const float4*)(Ap + k0 + 8);
      if (Wp) wv = *(const float4*)(Wp + k0 + 8);
    }
    __syncthreads();
#pragma unroll
    for (int kk = 0; kk < 8; ++kk) {
      float a[8], w[6];
      *(float4*)&a[0] = *(const float4*)&As[kk][ty * 8];
      *(float4*)&a[4] = *(const float4*)&As[kk][ty * 8 + 4];
#pragma unroll
      for (int j = 0; j < 6; ++j) w[j] = Ws[kk][tx * 6 + j];
#pragma unroll
      for (int i = 0; i < 8; ++i)
#pragma unroll
        for (int j = 0; j < 6; ++j)
          acc[i][j] = fmaf(a[i], w[j], acc[i][j]);
    }
    __syncthreads();
  }
  float* dst = Pq + (size_t)blockIdx.y * (MROWS * NPROJ);
#pragma unroll
  for (int i = 0; i < 8; ++i)
#pragma unroll
    for (int j = 0; j < 6; ++j)
      dst[(size_t)(row0 + ty * 8 + i) * NPROJ + tx * 6 + j] = acc[i][j];
}

__global__ __launch_bounds__(256)
void xpj_reduce(const float* __restrict__ Pq, float* __restrict__ xpb) {
  int idx = blockIdx.x * 256 + threadIdx.x;
  float s = 0.f;
#pragma unroll
  for (int q = 0; q < XKS; ++q)
    s += Pq[(size_t)q * (MROWS * NPROJ) + idx];
  xpb[idx] = s;
}

// ---------------------------------------------------------------------------
// Causal depthwise conv (k=4) + bias + SiLU, float4-vectorized.
// ---------------------------------------------------------------------------
__global__ __launch_bounds__(256)
void conv_silu_kernel(const float* __restrict__ xb, const float* __restrict__ cw,
                      const float* __restrict__ cb, float* __restrict__ xc) {
  int idx = (blockIdx.x * 256 + threadIdx.x) * 4;
  int d  = idx & (DINNER - 1);
  int ml = idx >> 11;
  int l  = ml & (LSEQ - 1);
  float4 W0 = *(const float4*)(cw + (d + 0) * 4);
  float4 W1 = *(const float4*)(cw + (d + 1) * 4);
  float4 W2 = *(const float4*)(cw + (d + 2) * 4);
  float4 W3 = *(const float4*)(cw + (d + 3) * 4);
  const float* base = xb + (size_t)ml * DINNER + d;
  float4 z4 = make_float4(0.f, 0.f, 0.f, 0.f);
  float4 r0  = *(const float4*)(base);
  float4 rm1 = (l >= 1) ? *(const float4*)(base - DINNER)     : z4;
  float4 rm2 = (l >= 2) ? *(const float4*)(base - 2 * DINNER) : z4;
  float4 rm3 = (l >= 3) ? *(const float4*)(base - 3 * DINNER) : z4;
  float4 bias = *(const float4*)(cb + d);
  float4 o;
  o.x = bias.x + r0.x * W0.w + rm1.x * W0.z + rm2.x * W0.y + rm3.x * W0.x;
  o.y = bias.y + r0.y * W1.w + rm1.y * W1.z + rm2.y * W1.y + rm3.y * W1.x;
  o.z = bias.z + r0.z * W2.w + rm1.z * W2.z + rm2.z * W2.y + rm3.z * W2.x;
  o.w = bias.w + r0.w * W3.w + rm1.w * W3.z + rm2.w * W3.y + rm3.w * W3.x;
  o.x = o.x / (1.f + expf(-o.x));
  o.y = o.y / (1.f + expf(-o.y));
  o.z = o.z / (1.f + expf(-o.z));
  o.w = o.w / (1.f + expf(-o.w));
  *(float4*)(xc + idx) = o;
}

// ---------------------------------------------------------------------------
// Chunked scan, h[16] in registers, one thread per (b, chunk, d).
// ---------------------------------------------------------------------------
__global__ __launch_bounds__(256)
void scan_chunk_kernel(const float* __restrict__ dt, const float* __restrict__ xp,
                       const float* __restrict__ xc, const float* __restrict__ A_log,
                       float* __restrict__ P, float* __restrict__ H) {
  __shared__ float sbc[CLEN][32];
  const int tid = threadIdx.x;
  const int bid = blockIdx.x;
  const int b  = bid >> 9;
  const int c  = (bid >> 3) & 63;
  const int dg = bid & 7;
  const int d  = dg * 256 + tid;
  const int m0 = b * LSEQ + c * CLEN;
  {
    int r = tid >> 3, q = (tid & 7) * 4;
    *(float4*)&sbc[r][q] = *(const float4*)(xp + (size_t)(m0 + r) * NPROJ + DTRANK + q);
  }
  float a2[DSTATE], h[DSTATE];
#pragma unroll
  for (int n = 0; n < DSTATE; ++n) {
    a2[n] = -expf(A_log[d * DSTATE + n]) * 1.44269504f;
    h[n] = 0.f;
  }
  float dtsum = 0.f;
  __syncthreads();

  const float* dtp = dt + (size_t)m0 * DINNER + d;
  const float* xcp = xc + (size_t)m0 * DINNER + d;
  float ndt = dtp[0], nxc = xcp[0];
  for (int s = 0; s < CLEN; ++s) {
    float dtv = ndt, xv = nxc;
    int sp = (s + 1 < CLEN) ? s + 1 : s;
    ndt = dtp[(size_t)sp * DINNER];
    nxc = xcp[(size_t)sp * DINNER];
    dtsum += dtv;
    float dtx = dtv * xv;
    float Bv[16];
    *(float4*)&Bv[0]  = *(const float4*)&sbc[s][0];
    *(float4*)&Bv[4]  = *(const float4*)&sbc[s][4];
    *(float4*)&Bv[8]  = *(const float4*)&sbc[s][8];
    *(float4*)&Bv[12] = *(const float4*)&sbc[s][12];
#pragma unroll
    for (int n = 0; n < DSTATE; ++n) {
      float a = exp2f(dtv * a2[n]);
      h[n] = fmaf(a, h[n], dtx * Bv[n]);
    }
  }
  size_t o = ((size_t)(b * NCHUNK + c) * DINNER + d) * DSTATE;
  float4* Hp = (float4*)(H + o);
  Hp[0] = make_float4(h[0], h[1], h[2], h[3]);
  Hp[1] = make_float4(h[4], h[5], h[6], h[7]);
  Hp[2] = make_float4(h[8], h[9], h[10], h[11]);
  Hp[3] = make_float4(h[12], h[13], h[14], h[15]);
  float p[16];
#pragma unroll
  for (int n = 0; n < DSTATE; ++n) p[n] = exp2f(a2[n] * dtsum);
  float4* Pp = (float4*)(P + o);
  Pp[0] = make_float4(p[0], p[1], p[2], p[3]);
  Pp[1] = make_float4(p[4], p[5], p[6], p[7]);
  Pp[2] = make_float4(p[8], p[9], p[10], p[11]);
  Pp[3] = make_float4(p[12], p[13], p[14], p[15]);
}

// ---------------------------------------------------------------------------
// Stitch: serial over chunks per (b, d, n); overwrites H[c] with h_init.
// ---------------------------------------------------------------------------
__global__ __launch_bounds__(256)
void stitch_kernel(const float* __restrict__ P, float* __restrict__ H) {
  int idx = blockIdx.x * 256 + threadIdx.x;
  int b = idx >> 15, e = idx & 32767;
  size_t base = (size_t)b * NCHUNK * 32768 + e;
  float h = 0.f;
  for (int c = 0; c < NCHUNK; ++c) {
    size_t o = base + (size_t)c * 32768;
    float p = P[o], q = H[o];
    H[o] = h;
    h = fmaf(p, h, q);
  }
}

// ---------------------------------------------------------------------------
// Output scan: recompute seeded with h_init, fused D-skip + silu(z) gate.
// dt and y alias (same buffer): each thread reads row s+1 before writing row s.
// ---------------------------------------------------------------------------
__global__ __launch_bounds__(256)
void scan_out_kernel(const float* dt, const float* __restrict__ xp,
                     const float* __restrict__ xc, const float* __restrict__ z,
                     const float* __restrict__ A_log, const float* __restrict__ Dp,
                     const float* __restrict__ Hinit, float* y) {
  __shared__ float sbc[CLEN][32];
  const int tid = threadIdx.x;
  const int bid = blockIdx.x;
  const int b  = bid >> 9;
  const int c  = (bid >> 3) & 63;
  const int dg = bid & 7;
  const int d  = dg * 256 + tid;
  const int m0 = b * LSEQ + c * CLEN;
  {
    int r = tid >> 3, q = (tid & 7) * 4;
    *(float4*)&sbc[r][q] = *(const float4*)(xp + (size_t)(m0 + r) * NPROJ + DTRANK + q);
  }
  float a2[DSTATE], h[DSTATE];
  size_t ho = ((size_t)(b * NCHUNK + c) * DINNER + d) * DSTATE;
  const float4* Hp = (const float4*)(Hinit + ho);
  float4 h0 = Hp[0], h1 = Hp[1], h2 = Hp[2], h3 = Hp[3];
  h[0]=h0.x; h[1]=h0.y; h[2]=h0.z; h[3]=h0.w;
  h[4]=h1.x; h[5]=h1.y; h[6]=h1.z; h[7]=h1.w;
  h[8]=h2.x; h[9]=h2.y; h[10]=h2.z; h[11]=h2.w;
  h[12]=h3.x; h[13]=h3.y; h[14]=h3.z; h[15]=h3.w;
#pragma unroll
  for (int n = 0; n < DSTATE; ++n)
    a2[n] = -expf(A_log[d * DSTATE + n]) * 1.44269504f;
  const float Dv = Dp[d];
  __syncthreads();

  const float* dtp = dt + (size_t)m0 * DINNER + d;
  const float* xcp = xc + (size_t)m0 * DINNER + d;
  const float* zp  = z  + (size_t)m0 * DINNER + d;
  float* yp = y + (size_t)m0 * DINNER + d;
  float ndt = dtp[0], nxc = xcp[0], nz = zp[0];
  for (int s = 0; s < CLEN; ++s) {
    float dtv = ndt, xv = nxc, zv = nz;
    int sp = (s + 1 < CLEN) ? s + 1 : s;
    ndt = dtp[(size_t)sp * DINNER];
    nxc = xcp[(size_t)sp * DINNER];
    nz  = zp[(size_t)sp * DINNER];
    float dtx = dtv * xv;
    float Bv[16], Cv[16];
    *(float4*)&Bv[0]  = *(const float4*)&sbc[s][0];
    *(float4*)&Bv[4]  = *(const float4*)&sbc[s][4];
    *(float4*)&Bv[8]  = *(const float4*)&sbc[s][8];
    *(float4*)&Bv[12] = *(const float4*)&sbc[s][12];
    *(float4*)&Cv[0]  = *(const float4*)&sbc[s][16];
    *(float4*)&Cv[4]  = *(const float4*)&sbc[s][20];
    *(float4*)&Cv[8]  = *(const float4*)&sbc[s][24];
    *(float4*)&Cv[12] = *(const float4*)&sbc[s][28];
    float yv = 0.f;
#pragma unroll
    for (int n = 0; n < DSTATE; ++n) {
      float a = exp2f(dtv * a2[n]);
      h[n] = fmaf(a, h[n], dtx * Bv[n]);
      yv = fmaf(h[n], Cv[n], yv);
    }
    yv = (yv + Dv * xv) * (zv / (1.f + expf(-zv)));
    yp[(size_t)s * DINNER] = yv;
  }
}

// ---------------------------------------------------------------------------
extern "C" void kernel_launch(void* const* d_in, const int* in_sizes, int n_in,
                              void* d_out, int out_size, void* d_ws, size_t ws_size,
                              hipStream_t stream) {
  const float* x          = (const float*)d_in[0];
  const float* in_proj_w  = (const float*)d_in[1];
  const float* conv_w     = (const float*)d_in[2];
  const float* conv_b     = (const float*)d_in[3];
  const float* x_proj_w   = (const float*)d_in[4];
  const float* dt_proj_w  = (const float*)d_in[5];
  const float* dt_proj_b  = (const float*)d_in[6];
  const float* A_log      = (const float*)d_in[7];
  const float* D_param    = (const float*)d_in[8];
  const float* out_proj_w = (const float*)d_in[9];
  float* out = (float*)d_out;
  float* ws  = (float*)d_ws;

  // workspace (floats); phase-reused regions:
  //   xb/dtr/y:  ws+0         [4096,2048] fp32, x_branch -> dt -> y
  //   zb:        +8388608     [4096,2048]
  //   xcb:       +16777216    [4096,2048]; ALSO: {xh,xl,wh,wl} planes during
  //              in_proj (before conv), {yh,yl} planes after scan_out
  //   xpb:       +25165824    [4096,96]
  //   Pbuf:      +25559040    scan P / xproj Pq; {oh,ol} planes after stitch
  //   Hbuf:      +29753344    scan H (h_init) — live through scan_out
  float* xb   = ws;
  float* dtr  = xb;
  float* zb   = ws + 8388608;
  float* xcb  = ws + 16777216;
  float* xpb  = ws + 25165824;
  float* Pbuf = ws + 25559040;
  float* Hbuf = ws + 29753344;
  float* Pq   = Pbuf;

  u16* xh = (u16*)(ws + 16777216);            // [4096][1024] bf16
  u16* xl = (u16*)(ws + 16777216 + 2097152);
  u16* wh = (u16*)(ws + 16777216 + 4194304);  // [4096][1024] bf16
  u16* wl = (u16*)(ws + 16777216 + 6291456);
  u16* yh = (u16*)(ws + 16777216);            // [4096][2048] bf16 (post-scan)
  u16* yl = (u16*)(ws + 16777216 + 4194304);
  u16* oh = (u16*)(ws + 25559040);            // [1024][2048] bf16 (post-stitch)
  u16* ol = (u16*)(ws + 25559040 + 1048576);

  dim3 blk(256);
  // 0. prep h/l planes for x and in_proj_w
  cvt_hl<<<4096, blk, 0, stream>>>((const float4*)x, (uint2*)xh, (uint2*)xl, 1048576);
  cvt_hl<<<4096, blk, 0, stream>>>((const float4*)in_proj_w, (uint2*)wh, (uint2*)wl, 1048576);
  // 1. in_proj (fused x_branch + z), dual output
  gemm_hl<<<dim3((MROWS / 128) * (2 * DINNER / 128)), blk, 0, stream>>>(
      xh, xl, wh, wl, xb, zb, MROWS, 2 * DINNER, DMODEL, DINNER, 4);
  // 2. causal depthwise conv + SiLU (x planes dead now)
  conv_silu_kernel<<<(MROWS * DINNER) / 1024, blk, 0, stream>>>(xb, conv_w, conv_b, xcb);
  // 3. x_proj split-K (atomic-free partials + reduce)
  xproj_splitk<<<dim3(MROWS / 128, XKS), blk, 0, stream>>>(xcb, x_proj_w, Pq);
  xpj_reduce<<<(MROWS * NPROJ) / 256, blk, 0, stream>>>(Pq, xpb);
  // 4. dt_proj with fused bias+softplus; overwrites x_branch
  gemm_tn<1><<<dim3(DINNER / 128, MROWS / 128), blk, 0, stream>>>(
      xpb, dt_proj_w, dtr, dt_proj_b, MROWS, DINNER, DTRANK, NPROJ);
  // 5. chunked scan: A (chunk transitions), B (stitch), C (output + gate)
  scan_chunk_kernel<<<dim3(BB * NCHUNK * 8), blk, 0, stream>>>(
      dtr, xpb, xcb, A_log, Pbuf, Hbuf);
  stitch_kernel<<<dim3(BB * DINNER * DSTATE / 256), blk, 0, stream>>>(Pbuf, Hbuf);
  scan_out_kernel<<<dim3(BB * NCHUNK * 8), blk, 0, stream>>>(
      dtr, xpb, xcb, zb, A_log, D_param, Hbuf, xb);
  // 6. prep h/l planes for y (xcb region, dead) and out_proj_w (Pbuf, dead)
  cvt_hl<<<8192, blk, 0, stream>>>((const float4*)xb, (uint2*)yh, (uint2*)yl, 2097152);
  cvt_hl<<<2048, blk, 0, stream>>>((const float4*)out_proj_w, (uint2*)oh, (uint2*)ol, 524288);
  // 7. out_proj
  gemm_hl<<<dim3((MROWS / 128) * (DMODEL / 128)), blk, 0, stream>>>(
      yh, yl, oh, ol, out, out, MROWS, DMODEL, DINNER, DMODEL, 1);
}

// Round 8
// 499.484 us; speedup vs baseline: 1.0439x; 1.0439x over previous
//
#include <hip/hip_runtime.h>
#include <math.h>

#define BB      2
#define LSEQ    2048
#define DMODEL  1024
#define DINNER  2048
#define DSTATE  16
#define DTRANK  64
#define NPROJ   96                 // DTRANK + 2*DSTATE
#define MROWS   (BB * LSEQ)        // 4096
#define NCHUNK  64
#define CLEN    32                 // LSEQ / NCHUNK
#define XKS     16                 // x_proj split-K factor

typedef unsigned short u16;
typedef short bf16x8 __attribute__((ext_vector_type(8)));
typedef float f32x4  __attribute__((ext_vector_type(4)));

// ---------------------------------------------------------------------------
// fp32 -> (hi, lo) bf16 split: v ~= hi + lo, hi = truncate, lo = RNE(residual)
// ---------------------------------------------------------------------------
struct HL { unsigned int hx, hy, lx, ly; };

__device__ __forceinline__ HL cvt4(float4 v) {
  unsigned int tx = __float_as_uint(v.x) & 0xFFFF0000u;
  unsigned int ty = __float_as_uint(v.y) & 0xFFFF0000u;
  unsigned int tz = __float_as_uint(v.z) & 0xFFFF0000u;
  unsigned int tw = __float_as_uint(v.w) & 0xFFFF0000u;
  HL r;
  r.hx = (tx >> 16) | ty;
  r.hy = (tz >> 16) | tw;
  float lx = v.x - __uint_as_float(tx);
  float ly = v.y - __uint_as_float(ty);
  float lz = v.z - __uint_as_float(tz);
  float lw = v.w - __uint_as_float(tw);
  unsigned int a = __float_as_uint(lx); a += 0x7FFFu + ((a >> 16) & 1u);
  unsigned int b = __float_as_uint(ly); b += 0x7FFFu + ((b >> 16) & 1u);
  unsigned int c = __float_as_uint(lz); c += 0x7FFFu + ((c >> 16) & 1u);
  unsigned int d = __float_as_uint(lw); d += 0x7FFFu + ((d >> 16) & 1u);
  r.lx = (a >> 16) | (b & 0xFFFF0000u);
  r.ly = (c >> 16) | (d & 0xFFFF0000u);
  return r;
}

// prep: fp32 array -> hi/lo bf16 planes
__global__ __launch_bounds__(256)
void cvt_hl(const float4* __restrict__ src, uint2* __restrict__ dh,
            uint2* __restrict__ dl, int n4) {
  int i = blockIdx.x * 256 + threadIdx.x;
  if (i < n4) {
    HL r = cvt4(src[i]);
    dh[i] = make_uint2(r.hx, r.hy);
    dl[i] = make_uint2(r.lx, r.ly);
  }
}

// ---------------------------------------------------------------------------
// global_load_lds width-16 wrapper (LDS dest: wave-uniform base + lane*16)
// ---------------------------------------------------------------------------
__device__ __forceinline__ void gll16(const void* g, void* l) {
  __builtin_amdgcn_global_load_lds(
      (const __attribute__((address_space(1))) void*)g,
      (__attribute__((address_space(3))) void*)l, 16, 0, 0);
}

// ---------------------------------------------------------------------------
// 256x256 split-bf16 MFMA GEMM (in_proj): C = A@B^T from h/l planes.
// BK=32, 512 thr (8 waves 2x4; wave tile 128x64 = 8x4 frags; 96 MFMA vs
// 24 ds_read_b128 per wave per K-step -> MFMA-bound).  128 KB dbuf LDS,
// ONE barrier per K-step: STAGE(t+1) issued before compute(t), vmcnt(0)
// right before the barrier (loads fly under the MFMAs).  Same validated
// source-permuted XOR swizzle.  Dual output at col boundary Nout (256-
// aligned).  grid = (M/256)*(N/256), % 8 == 0.
// ---------------------------------------------------------------------------
__global__ __launch_bounds__(512, 1)
void gemm_hl256(const u16* __restrict__ Ahp, const u16* __restrict__ Alp,
                const u16* __restrict__ Bhp, const u16* __restrict__ Blp,
                float* __restrict__ C0, float* __restrict__ C1,
                int M, int N, int K, int Nout, int XC_C) {
  __shared__ __align__(16) u16 L[2][4][256 * 32];   // 128 KB

  const int tid = threadIdx.x;
  const int nbx = N >> 8, nby = M >> 8;
  const int xcd = blockIdx.x & 7;
  const int pos = blockIdx.x >> 3;
  const int cr = xcd / XC_C, cc = xcd - cr * XC_C;
  const int GCc = nbx / XC_C;
  const int GR  = (nby * XC_C) >> 3;
  const int by = cr * GR + pos / GCc;
  const int bx = cc * GCc + pos % GCc;
  const int row0 = by << 8, col0 = bx << 8;

  const int lane = tid & 63, w = tid >> 6;           // 8 waves
  const int wr = w >> 2, wc = w & 3;                 // 2 x 4
  const int fr = lane & 15, g = lane >> 4;
  const int lrow = lane >> 2, lslot = lane & 3;

  f32x4 acc[8][4] = {};
  const int NT = K >> 5;

  // stage tile (k0) into buffer pb: per wave 2 row-groups x 4 planes
#define STAGE256(pb, k0)                                                   \
  {                                                                        \
    _Pragma("unroll")                                                      \
    for (int s = 0; s < 2; ++s) {                                          \
      const int r = w * 32 + s * 16 + lrow;                                \
      const int csrc = (lslot ^ ((r >> 1) & 3)) << 3;                      \
      const size_t gA = (size_t)(row0 + r) * K + (k0) + csrc;              \
      const size_t gB = (size_t)(col0 + r) * K + (k0) + csrc;              \
      const int lb = w * 1024 + s * 512;                                   \
      gll16(Ahp + gA, &L[pb][0][lb]);                                      \
      gll16(Alp + gA, &L[pb][1][lb]);                                      \
      gll16(Bhp + gB, &L[pb][2][lb]);                                      \
      gll16(Blp + gB, &L[pb][3][lb]);                                      \
    }                                                                      \
  }

  STAGE256(0, 0);
  asm volatile("s_waitcnt vmcnt(0)" ::: "memory");
  __syncthreads();

  int p = 0;
  for (int t = 0; t < NT; ++t) {
    const bool pf = (t + 1 < NT);
    if (pf) STAGE256(p ^ 1, (t + 1) * 32);

    bf16x8 bh[4], bl[4];
#pragma unroll
    for (int j = 0; j < 4; ++j) {
      const int rb = wc * 64 + j * 16 + fr;
      const int o = rb * 32 + ((g ^ ((rb >> 1) & 3)) << 3);
      bh[j] = *(const bf16x8*)&L[p][2][o];
      bl[j] = *(const bf16x8*)&L[p][3][o];
    }
#pragma unroll
    for (int i = 0; i < 8; ++i) {
      const int ra = wr * 128 + i * 16 + fr;
      const int o = ra * 32 + ((g ^ ((ra >> 1) & 3)) << 3);
      bf16x8 ah = *(const bf16x8*)&L[p][0][o];
      bf16x8 al = *(const bf16x8*)&L[p][1][o];
#pragma unroll
      for (int j = 0; j < 4; ++j) {
        acc[i][j] = __builtin_amdgcn_mfma_f32_16x16x32_bf16(al, bh[j], acc[i][j], 0, 0, 0);
        acc[i][j] = __builtin_amdgcn_mfma_f32_16x16x32_bf16(ah, bl[j], acc[i][j], 0, 0, 0);
        acc[i][j] = __builtin_amdgcn_mfma_f32_16x16x32_bf16(ah, bh[j], acc[i][j], 0, 0, 0);
      }
    }
    if (pf) {
      asm volatile("s_waitcnt vmcnt(0)" ::: "memory");
      __syncthreads();
    }
    p ^= 1;
  }

  // C/D layout: col = lane&15, row = (lane>>4)*4 + reg  (m89-verified)
  float* Cd;
  int cc0;
  if (C1 != nullptr && col0 >= Nout) { Cd = C1; cc0 = col0 - Nout; }
  else                               { Cd = C0; cc0 = col0; }
#pragma unroll
  for (int i = 0; i < 8; ++i) {
    const int rbase = row0 + wr * 128 + i * 16 + (lane >> 4) * 4;
#pragma unroll
    for (int j = 0; j < 4; ++j) {
      const int cfull = cc0 + wc * 64 + j * 16 + fr;
#pragma unroll
      for (int r = 0; r < 4; ++r)
        Cd[(size_t)(rbase + r) * Nout + cfull] = acc[i][j][r];
    }
  }
#undef STAGE256
}

// ---------------------------------------------------------------------------
// 128x128 split-bf16 MFMA GEMM (out_proj): unchanged validated kernel.
// ---------------------------------------------------------------------------
__global__ __launch_bounds__(256, 3)
void gemm_hl(const u16* __restrict__ Ahp, const u16* __restrict__ Alp,
             const u16* __restrict__ Bhp, const u16* __restrict__ Blp,
             float* __restrict__ C0, float* __restrict__ C1,
             int M, int N, int K, int Nout, int XC_C) {
  __shared__ __align__(16) u16 L[4][128 * 32];   // 32 KB

  const int tid = threadIdx.x;
  const int nbx = N >> 7, nby = M >> 7;
  const int xcd = blockIdx.x & 7;
  const int pos = blockIdx.x >> 3;
  const int cr = xcd / XC_C, cc = xcd - cr * XC_C;
  const int GCc = nbx / XC_C;
  const int GR  = (nby * XC_C) >> 3;
  const int by = cr * GR + pos / GCc;
  const int bx = cc * GCc + pos % GCc;
  const int row0 = by << 7, col0 = bx << 7;

  const int lane = tid & 63, w = tid >> 6;
  const int wr = w >> 1, wc = w & 1;
  const int fr = lane & 15, g = lane >> 4;
  const int lrow = lane >> 2, lslot = lane & 3;

  f32x4 acc[4][4] = {};

  for (int k0 = 0; k0 < K; k0 += 32) {
#pragma unroll
    for (int s = 0; s < 2; ++s) {
      const int r = w * 32 + s * 16 + lrow;
      const int csrc = (lslot ^ ((r >> 1) & 3)) << 3;
      const size_t gA = (size_t)(row0 + r) * K + k0 + csrc;
      const size_t gB = (size_t)(col0 + r) * K + k0 + csrc;
      const int lb = w * 1024 + s * 512;
      gll16(Ahp + gA, &L[0][lb]);
      gll16(Alp + gA, &L[1][lb]);
      gll16(Bhp + gB, &L[2][lb]);
      gll16(Blp + gB, &L[3][lb]);
    }
    __syncthreads();

    bf16x8 bh[4], bl[4];
#pragma unroll
    for (int j = 0; j < 4; ++j) {
      const int rb = wc * 64 + j * 16 + fr;
      const int o = rb * 32 + ((g ^ ((rb >> 1) & 3)) << 3);
      bh[j] = *(const bf16x8*)&L[2][o];
      bl[j] = *(const bf16x8*)&L[3][o];
    }
#pragma unroll
    for (int i = 0; i < 4; ++i) {
      const int ra = wr * 64 + i * 16 + fr;
      const int o = ra * 32 + ((g ^ ((ra >> 1) & 3)) << 3);
      bf16x8 ah = *(const bf16x8*)&L[0][o];
      bf16x8 al = *(const bf16x8*)&L[1][o];
#pragma unroll
      for (int j = 0; j < 4; ++j) {
        acc[i][j] = __builtin_amdgcn_mfma_f32_16x16x32_bf16(al, bh[j], acc[i][j], 0, 0, 0);
        acc[i][j] = __builtin_amdgcn_mfma_f32_16x16x32_bf16(ah, bl[j], acc[i][j], 0, 0, 0);
        acc[i][j] = __builtin_amdgcn_mfma_f32_16x16x32_bf16(ah, bh[j], acc[i][j], 0, 0, 0);
      }
    }
    __syncthreads();
  }

  float* Cd;
  int cc0;
  if (C1 != nullptr && col0 >= Nout) { Cd = C1; cc0 = col0 - Nout; }
  else                               { Cd = C0; cc0 = col0; }
#pragma unroll
  for (int i = 0; i < 4; ++i) {
    const int rbase = row0 + wr * 64 + i * 16 + (lane >> 4) * 4;
#pragma unroll
    for (int j = 0; j < 4; ++j) {
      const int cfull = cc0 + wc * 64 + j * 16 + fr;
#pragma unroll
      for (int r = 0; r < 4; ++r)
        Cd[(size_t)(rbase + r) * Nout + cfull] = acc[i][j][r];
    }
  }
}

// ---------------------------------------------------------------------------
// fp32 GEMM (dt_proj only): C = softplus(A@B^T + bias[col]); reg prefetch.
// ---------------------------------------------------------------------------
template <int ACT>
__global__ __launch_bounds__(256)
void gemm_tn(const float* __restrict__ A, const float* __restrict__ B,
             float* __restrict__ C, const float* __restrict__ bias,
             int M, int N, int K, int lda) {
  __shared__ float As[8][128];
  __shared__ float Bs[8][128];
  const int tid  = threadIdx.x;
  const int row0 = blockIdx.y * 128;
  const int col0 = blockIdx.x * 128;
  const int tx = tid & 15, ty = tid >> 4;
  const int lr = tid >> 1;
  const int lk = (tid & 1) * 4;

  float acc[8][8];
#pragma unroll
  for (int i = 0; i < 8; ++i)
#pragma unroll
    for (int j = 0; j < 8; ++j) acc[i][j] = 0.f;

  const float* Aptr = A + (size_t)(row0 + lr) * lda + lk;
  const int bcol = col0 + lr;
  const float* Bptr = (bcol < N) ? (B + (size_t)bcol * K + lk) : nullptr;

  float4 av = *(const float4*)(Aptr);
  float4 bv = Bptr ? *(const float4*)(Bptr) : make_float4(0.f, 0.f, 0.f, 0.f);

  for (int k0 = 0; k0 < K; k0 += 8) {
    As[lk + 0][lr] = av.x; As[lk + 1][lr] = av.y;
    As[lk + 2][lr] = av.z; As[lk + 3][lr] = av.w;
    Bs[lk + 0][lr] = bv.x; Bs[lk + 1][lr] = bv.y;
    Bs[lk + 2][lr] = bv.z; Bs[lk + 3][lr] = bv.w;
    if (k0 + 8 < K) {
      av = *(const float4*)(Aptr + k0 + 8);
      if (Bptr) bv = *(const float4*)(Bptr + k0 + 8);
    }
    __syncthreads();
#pragma unroll
    for (int k = 0; k < 8; ++k) {
      float a[8], b[8];
      *(float4*)&a[0] = *(const float4*)&As[k][ty * 4];
      *(float4*)&a[4] = *(const float4*)&As[k][64 + ty * 4];
      *(float4*)&b[0] = *(const float4*)&Bs[k][tx * 4];
      *(float4*)&b[4] = *(const float4*)&Bs[k][64 + tx * 4];
#pragma unroll
      for (int i = 0; i < 8; ++i)
#pragma unroll
        for (int j = 0; j < 8; ++j)
          acc[i][j] = fmaf(a[i], b[j], acc[i][j]);
    }
    __syncthreads();
  }

#pragma unroll
  for (int ih = 0; ih < 2; ++ih) {
#pragma unroll
    for (int i2 = 0; i2 < 4; ++i2) {
      int r = row0 + ih * 64 + ty * 4 + i2;
      if (r >= M) continue;
#pragma unroll
      for (int jh = 0; jh < 2; ++jh) {
        int c = col0 + jh * 64 + tx * 4;
        float vv[4];
#pragma unroll
        for (int j = 0; j < 4; ++j) {
          float v = acc[ih * 4 + i2][jh * 4 + j];
          if (ACT == 1) {
            v += bias[c + j];
            v = (v > 20.f) ? v : log1pf(expf(v));   // softplus
          }
          vv[j] = v;
        }
        if (c + 3 < N) {
          *(float4*)(C + (size_t)r * N + c) = make_float4(vv[0], vv[1], vv[2], vv[3]);
        } else {
          for (int j = 0; j < 4; ++j)
            if (c + j < N) C[(size_t)r * N + c + j] = vv[j];
        }
      }
    }
  }
}

// ---------------------------------------------------------------------------
// x_proj split-K, atomic-free: Pq[q][4096][96] = A[:, q-slice] @ W[:, q-slice]^T
// ---------------------------------------------------------------------------
__global__ __launch_bounds__(256)
void xproj_splitk(const float* __restrict__ A, const float* __restrict__ W,
                  float* __restrict__ Pq) {
  __shared__ float As[8][128];
  __shared__ float Ws[8][96];
  const int tid  = threadIdx.x;
  const int row0 = blockIdx.x * 128;
  const int k0b  = blockIdx.y * (DINNER / XKS);
  const int tx = tid & 15, ty = tid >> 4;
  const int lr = tid >> 1, lk = (tid & 1) * 4;

  float acc[8][6];
#pragma unroll
  for (int i = 0; i < 8; ++i)
#pragma unroll
    for (int j = 0; j < 6; ++j) acc[i][j] = 0.f;

  const float* Ap = A + (size_t)(row0 + lr) * DINNER + lk;
  const float* Wp = (tid < 192) ? (W + (size_t)(tid >> 1) * DINNER + (tid & 1) * 4)
                                : nullptr;
  float4 av = *(const float4*)(Ap + k0b);
  float4 wv = Wp ? *(const float4*)(Wp + k0b) : make_float4(0.f, 0.f, 0.f, 0.f);

  for (int k0 = k0b; k0 < k0b + DINNER / XKS; k0 += 8) {
    As[lk + 0][lr] = av.x; As[lk + 1][lr] = av.y;
    As[lk + 2][lr] = av.z; As[lk + 3][lr] = av.w;
    if (Wp) {
      int j = tid >> 1, kk = (tid & 1) * 4;
      Ws[kk + 0][j] = wv.x; Ws[kk + 1][j] = wv.y;
      Ws[kk + 2][j] = wv.z; Ws[kk + 3][j] = wv.w;
    }
    if (k0 + 8 < k0b + DINNER / XKS) {
      av = *(const float4*)(Ap + k0 + 8);
      if (Wp) wv = *(const float4*)(Wp + k0 + 8);
    }
    __syncthreads();
#pragma unroll
    for (int kk = 0; kk < 8; ++kk) {
      float a[8], w[6];
      *(float4*)&a[0] = *(const float4*)&As[kk][ty * 8];
      *(float4*)&a[4] = *(const float4*)&As[kk][ty * 8 + 4];
#pragma unroll
      for (int j = 0; j < 6; ++j) w[j] = Ws[kk][tx * 6 + j];
#pragma unroll
      for (int i = 0; i < 8; ++i)
#pragma unroll
        for (int j = 0; j < 6; ++j)
          acc[i][j] = fmaf(a[i], w[j], acc[i][j]);
    }
    __syncthreads();
  }
  float* dst = Pq + (size_t)blockIdx.y * (MROWS * NPROJ);
#pragma unroll
  for (int i = 0; i < 8; ++i)
#pragma unroll
    for (int j = 0; j < 6; ++j)
      dst[(size_t)(row0 + ty * 8 + i) * NPROJ + tx * 6 + j] = acc[i][j];
}

__global__ __launch_bounds__(256)
void xpj_reduce(const float* __restrict__ Pq, float* __restrict__ xpb) {
  int idx = blockIdx.x * 256 + threadIdx.x;
  float s = 0.f;
#pragma unroll
  for (int q = 0; q < XKS; ++q)
    s += Pq[(size_t)q * (MROWS * NPROJ) + idx];
  xpb[idx] = s;
}

// ---------------------------------------------------------------------------
// Causal depthwise conv (k=4) + bias + SiLU, float4-vectorized.
// ---------------------------------------------------------------------------
__global__ __launch_bounds__(256)
void conv_silu_kernel(const float* __restrict__ xb, const float* __restrict__ cw,
                      const float* __restrict__ cb, float* __restrict__ xc) {
  int idx = (blockIdx.x * 256 + threadIdx.x) * 4;
  int d  = idx & (DINNER - 1);
  int ml = idx >> 11;
  int l  = ml & (LSEQ - 1);
  float4 W0 = *(const float4*)(cw + (d + 0) * 4);
  float4 W1 = *(const float4*)(cw + (d + 1) * 4);
  float4 W2 = *(const float4*)(cw + (d + 2) * 4);
  float4 W3 = *(const float4*)(cw + (d + 3) * 4);
  const float* base = xb + (size_t)ml * DINNER + d;
  float4 z4 = make_float4(0.f, 0.f, 0.f, 0.f);
  float4 r0  = *(const float4*)(base);
  float4 rm1 = (l >= 1) ? *(const float4*)(base - DINNER)     : z4;
  float4 rm2 = (l >= 2) ? *(const float4*)(base - 2 * DINNER) : z4;
  float4 rm3 = (l >= 3) ? *(const float4*)(base - 3 * DINNER) : z4;
  float4 bias = *(const float4*)(cb + d);
  float4 o;
  o.x = bias.x + r0.x * W0.w + rm1.x * W0.z + rm2.x * W0.y + rm3.x * W0.x;
  o.y = bias.y + r0.y * W1.w + rm1.y * W1.z + rm2.y * W1.y + rm3.y * W1.x;
  o.z = bias.z + r0.z * W2.w + rm1.z * W2.z + rm2.z * W2.y + rm3.z * W2.x;
  o.w = bias.w + r0.w * W3.w + rm1.w * W3.z + rm2.w * W3.y + rm3.w * W3.x;
  o.x = o.x / (1.f + expf(-o.x));
  o.y = o.y / (1.f + expf(-o.y));
  o.z = o.z / (1.f + expf(-o.z));
  o.w = o.w / (1.f + expf(-o.w));
  *(float4*)(xc + idx) = o;
}

// ---------------------------------------------------------------------------
// Chunked scan, h[16] in registers, one thread per (b, chunk, d).
// ---------------------------------------------------------------------------
__global__ __launch_bounds__(256)
void scan_chunk_kernel(const float* __restrict__ dt, const float* __restrict__ xp,
                       const float* __restrict__ xc, const float* __restrict__ A_log,
                       float* __restrict__ P, float* __restrict__ H) {
  __shared__ float sbc[CLEN][32];
  const int tid = threadIdx.x;
  const int bid = blockIdx.x;
  const int b  = bid >> 9;
  const int c  = (bid >> 3) & 63;
  const int dg = bid & 7;
  const int d  = dg * 256 + tid;
  const int m0 = b * LSEQ + c * CLEN;
  {
    int r = tid >> 3, q = (tid & 7) * 4;
    *(float4*)&sbc[r][q] = *(const float4*)(xp + (size_t)(m0 + r) * NPROJ + DTRANK + q);
  }
  float a2[DSTATE], h[DSTATE];
#pragma unroll
  for (int n = 0; n < DSTATE; ++n) {
    a2[n] = -expf(A_log[d * DSTATE + n]) * 1.44269504f;
    h[n] = 0.f;
  }
  float dtsum = 0.f;
  __syncthreads();

  const float* dtp = dt + (size_t)m0 * DINNER + d;
  const float* xcp = xc + (size_t)m0 * DINNER + d;
  float ndt = dtp[0], nxc = xcp[0];
  for (int s = 0; s < CLEN; ++s) {
    float dtv = ndt, xv = nxc;
    int sp = (s + 1 < CLEN) ? s + 1 : s;
    ndt = dtp[(size_t)sp * DINNER];
    nxc = xcp[(size_t)sp * DINNER];
    dtsum += dtv;
    float dtx = dtv * xv;
    float Bv[16];
    *(float4*)&Bv[0]  = *(const float4*)&sbc[s][0];
    *(float4*)&Bv[4]  = *(const float4*)&sbc[s][4];
    *(float4*)&Bv[8]  = *(const float4*)&sbc[s][8];
    *(float4*)&Bv[12] = *(const float4*)&sbc[s][12];
#pragma unroll
    for (int n = 0; n < DSTATE; ++n) {
      float a = exp2f(dtv * a2[n]);
      h[n] = fmaf(a, h[n], dtx * Bv[n]);
    }
  }
  size_t o = ((size_t)(b * NCHUNK + c) * DINNER + d) * DSTATE;
  float4* Hp = (float4*)(H + o);
  Hp[0] = make_float4(h[0], h[1], h[2], h[3]);
  Hp[1] = make_float4(h[4], h[5], h[6], h[7]);
  Hp[2] = make_float4(h[8], h[9], h[10], h[11]);
  Hp[3] = make_float4(h[12], h[13], h[14], h[15]);
  float p[16];
#pragma unroll
  for (int n = 0; n < DSTATE; ++n) p[n] = exp2f(a2[n] * dtsum);
  float4* Pp = (float4*)(P + o);
  Pp[0] = make_float4(p[0], p[1], p[2], p[3]);
  Pp[1] = make_float4(p[4], p[5], p[6], p[7]);
  Pp[2] = make_float4(p[8], p[9], p[10], p[11]);
  Pp[3] = make_float4(p[12], p[13], p[14], p[15]);
}

// ---------------------------------------------------------------------------
// Stitch: serial over chunks per (b, d, n); overwrites H[c] with h_init.
// ---------------------------------------------------------------------------
__global__ __launch_bounds__(256)
void stitch_kernel(const float* __restrict__ P, float* __restrict__ H) {
  int idx = blockIdx.x * 256 + threadIdx.x;
  int b = idx >> 15, e = idx & 32767;
  size_t base = (size_t)b * NCHUNK * 32768 + e;
  float h = 0.f;
  for (int c = 0; c < NCHUNK; ++c) {
    size_t o = base + (size_t)c * 32768;
    float p = P[o], q = H[o];
    H[o] = h;
    h = fmaf(p, h, q);
  }
}

// ---------------------------------------------------------------------------
// Output scan: recompute seeded with h_init, fused D-skip + silu(z) gate.
// dt and y alias (same buffer): each thread reads row s+1 before writing row s.
// ---------------------------------------------------------------------------
__global__ __launch_bounds__(256)
void scan_out_kernel(const float* dt, const float* __restrict__ xp,
                     const float* __restrict__ xc, const float* __restrict__ z,
                     const float* __restrict__ A_log, const float* __restrict__ Dp,
                     const float* __restrict__ Hinit, float* y) {
  __shared__ float sbc[CLEN][32];
  const int tid = threadIdx.x;
  const int bid = blockIdx.x;
  const int b  = bid >> 9;
  const int c  = (bid >> 3) & 63;
  const int dg = bid & 7;
  const int d  = dg * 256 + tid;
  const int m0 = b * LSEQ + c * CLEN;
  {
    int r = tid >> 3, q = (tid & 7) * 4;
    *(float4*)&sbc[r][q] = *(const float4*)(xp + (size_t)(m0 + r) * NPROJ + DTRANK + q);
  }
  float a2[DSTATE], h[DSTATE];
  size_t ho = ((size_t)(b * NCHUNK + c) * DINNER + d) * DSTATE;
  const float4* Hp = (const float4*)(Hinit + ho);
  float4 h0 = Hp[0], h1 = Hp[1], h2 = Hp[2], h3 = Hp[3];
  h[0]=h0.x; h[1]=h0.y; h[2]=h0.z; h[3]=h0.w;
  h[4]=h1.x; h[5]=h1.y; h[6]=h1.z; h[7]=h1.w;
  h[8]=h2.x; h[9]=h2.y; h[10]=h2.z; h[11]=h2.w;
  h[12]=h3.x; h[13]=h3.y; h[14]=h3.z; h[15]=h3.w;
#pragma unroll
  for (int n = 0; n < DSTATE; ++n)
    a2[n] = -expf(A_log[d * DSTATE + n]) * 1.44269504f;
  const float Dv = Dp[d];
  __syncthreads();

  const float* dtp = dt + (size_t)m0 * DINNER + d;
  const float* xcp = xc + (size_t)m0 * DINNER + d;
  const float* zp  = z  + (size_t)m0 * DINNER + d;
  float* yp = y + (size_t)m0 * DINNER + d;
  float ndt = dtp[0], nxc = xcp[0], nz = zp[0];
  for (int s = 0; s < CLEN; ++s) {
    float dtv = ndt, xv = nxc, zv = nz;
    int sp = (s + 1 < CLEN) ? s + 1 : s;
    ndt = dtp[(size_t)sp * DINNER];
    nxc = xcp[(size_t)sp * DINNER];
    nz  = zp[(size_t)sp * DINNER];
    float dtx = dtv * xv;
    float Bv[16], Cv[16];
    *(float4*)&Bv[0]  = *(const float4*)&sbc[s][0];
    *(float4*)&Bv[4]  = *(const float4*)&sbc[s][4];
    *(float4*)&Bv[8]  = *(const float4*)&sbc[s][8];
    *(float4*)&Bv[12] = *(const float4*)&sbc[s][12];
    *(float4*)&Cv[0]  = *(const float4*)&sbc[s][16];
    *(float4*)&Cv[4]  = *(const float4*)&sbc[s][20];
    *(float4*)&Cv[8]  = *(const float4*)&sbc[s][24];
    *(float4*)&Cv[12] = *(const float4*)&sbc[s][28];
    float yv = 0.f;
#pragma unroll
    for (int n = 0; n < DSTATE; ++n) {
      float a = exp2f(dtv * a2[n]);
      h[n] = fmaf(a, h[n], dtx * Bv[n]);
      yv = fmaf(h[n], Cv[n], yv);
    }
    yv = (yv + Dv * xv) * (zv / (1.f + expf(-zv)));
    yp[(size_t)s * DINNER] = yv;
  }
}

// ---------------------------------------------------------------------------
extern "C" void kernel_launch(void* const* d_in, const int* in_sizes, int n_in,
                              void* d_out, int out_size, void* d_ws, size_t ws_size,
                              hipStream_t stream) {
  const float* x          = (const float*)d_in[0];
  const float* in_proj_w  = (const float*)d_in[1];
  const float* conv_w     = (const float*)d_in[2];
  const float* conv_b     = (const float*)d_in[3];
  const float* x_proj_w   = (const float*)d_in[4];
  const float* dt_proj_w  = (const float*)d_in[5];
  const float* dt_proj_b  = (const float*)d_in[6];
  const float* A_log      = (const float*)d_in[7];
  const float* D_param    = (const float*)d_in[8];
  const float* out_proj_w = (const float*)d_in[9];
  float* out = (float*)d_out;
  float* ws  = (float*)d_ws;

  // workspace (floats); phase-reused regions (same as Round 7)
  float* xb   = ws;
  float* dtr  = xb;
  float* zb   = ws + 8388608;
  float* xcb  = ws + 16777216;
  float* xpb  = ws + 25165824;
  float* Pbuf = ws + 25559040;
  float* Hbuf = ws + 29753344;
  float* Pq   = Pbuf;

  u16* xh = (u16*)(ws + 16777216);            // [4096][1024] bf16
  u16* xl = (u16*)(ws + 16777216 + 2097152);
  u16* wh = (u16*)(ws + 16777216 + 4194304);  // [4096][1024] bf16
  u16* wl = (u16*)(ws + 16777216 + 6291456);
  u16* yh = (u16*)(ws + 16777216);            // [4096][2048] bf16 (post-scan)
  u16* yl = (u16*)(ws + 16777216 + 4194304);
  u16* oh = (u16*)(ws + 25559040);            // [1024][2048] bf16 (post-stitch)
  u16* ol = (u16*)(ws + 25559040 + 1048576);

  dim3 blk(256);
  // 0. prep h/l planes for x and in_proj_w
  cvt_hl<<<4096, blk, 0, stream>>>((const float4*)x, (uint2*)xh, (uint2*)xl, 1048576);
  cvt_hl<<<4096, blk, 0, stream>>>((const float4*)in_proj_w, (uint2*)wh, (uint2*)wl, 1048576);
  // 1. in_proj (fused x_branch + z): 256x256 2-phase MFMA GEMM, dual output
  gemm_hl256<<<dim3((MROWS / 256) * (2 * DINNER / 256)), dim3(512), 0, stream>>>(
      xh, xl, wh, wl, xb, zb, MROWS, 2 * DINNER, DMODEL, DINNER, 4);
  // 2. causal depthwise conv + SiLU
  conv_silu_kernel<<<(MROWS * DINNER) / 1024, blk, 0, stream>>>(xb, conv_w, conv_b, xcb);
  // 3. x_proj split-K (atomic-free partials + reduce)
  xproj_splitk<<<dim3(MROWS / 128, XKS), blk, 0, stream>>>(xcb, x_proj_w, Pq);
  xpj_reduce<<<(MROWS * NPROJ) / 256, blk, 0, stream>>>(Pq, xpb);
  // 4. dt_proj with fused bias+softplus; overwrites x_branch
  gemm_tn<1><<<dim3(DINNER / 128, MROWS / 128), blk, 0, stream>>>(
      xpb, dt_proj_w, dtr, dt_proj_b, MROWS, DINNER, DTRANK, NPROJ);
  // 5. chunked scan: A (chunk transitions), B (stitch), C (output + gate)
  scan_chunk_kernel<<<dim3(BB * NCHUNK * 8), blk, 0, stream>>>(
      dtr, xpb, xcb, A_log, Pbuf, Hbuf);
  stitch_kernel<<<dim3(BB * DINNER * DSTATE / 256), blk, 0, stream>>>(Pbuf, Hbuf);
  scan_out_kernel<<<dim3(BB * NCHUNK * 8), blk, 0, stream>>>(
      dtr, xpb, xcb, zb, A_log, D_param, Hbuf, xb);
  // 6. prep h/l planes for y (xcb region, dead) and out_proj_w (Pbuf, dead)
  cvt_hl<<<8192, blk, 0, stream>>>((const float4*)xb, (uint2*)yh, (uint2*)yl, 2097152);
  cvt_hl<<<2048, blk, 0, stream>>>((const float4*)out_proj_w, (uint2*)oh, (uint2*)ol, 524288);
  // 7. out_proj (128x128 path)
  gemm_hl<<<dim3((MROWS / 128) * (DMODEL / 128)), blk, 0, stream>>>(
      yh, yl, oh, ol, out, out, MROWS, DMODEL, DINNER, DMODEL, 1);
}